// Round 7
// baseline (290.699 us; speedup 1.0000x reference)
//
#include <hip/hip_runtime.h>
#include <hip/hip_bf16.h>
#include <cstddef>
#include <cstdint>

// Shapes (hard-coded from reference): B=1, C=256, D=H=W=16 -> N=4096
// heads=8, hd=32, GROUPS=32 (8 ch/group)
#define NTOK 4096
#define CCH  256
#define HEADS 8
#define HD    32
// (1/sqrt(32)) * log2(e): scores computed directly in log2 domain
#define QSCALE 0.25503494f

typedef __attribute__((ext_vector_type(8)))  short short8;
typedef __attribute__((ext_vector_type(4)))  short short4v;
typedef __attribute__((ext_vector_type(16))) float f32x16;

__device__ __forceinline__ unsigned short f2bf(float x) {
    unsigned u = __builtin_bit_cast(unsigned, x);
    u = (u + 0x7fffu + ((u >> 16) & 1u)) >> 16;   // RNE truncate to bf16
    return (unsigned short)u;
}
// packed bf16 pair via HW cvt: low16 = bf16(a), high16 = bf16(b)
__device__ __forceinline__ unsigned packbf2(float a, float b) {
    unsigned r;
    asm("v_cvt_pk_bf16_f32 %0, %1, %2" : "=v"(r) : "v"(a), "v"(b));
    return r;
}
// hardware 2^x (1 instr; avoids libm exp2f sequence)
__device__ __forceinline__ float exp2hw(float x) {
    float r;
    asm("v_exp_f32 %0, %1" : "=v"(r) : "v"(x));
    return r;
}

// async global->LDS, 16B per lane, linear LDS dest (wave-uniform base + lane*16)
#define GLDS(gsrc, ldst) \
  __builtin_amdgcn_global_load_lds((const __attribute__((address_space(1))) unsigned int*)(const void*)(gsrc), \
                                   (__attribute__((address_space(3))) unsigned int*)(void*)(ldst), 16, 0, 0)

#define CROW(r, hi) (((r) & 3) + 8 * ((r) >> 2) + 4 * (hi))

// ---------------------------------------------------------------------------
// Kernel 1: per-channel partial sums for GroupNorm. 256 blocks = 1 per channel.
//   part[c] = {sum, sumsq} over the channel's 4096 elements.
// ---------------------------------------------------------------------------
__global__ __launch_bounds__(256) void gn_part_kernel(
    const float* __restrict__ X, float2* __restrict__ part)
{
    int c = blockIdx.x, tid = threadIdx.x;
    const float4* xr = (const float4*)(X + (size_t)c * NTOK);
    float s = 0.f, ss = 0.f;
    #pragma unroll
    for (int i = 0; i < 4; i++) {
        float4 v = xr[tid + i * 256];
        s  += (v.x + v.y) + (v.z + v.w);
        ss += (v.x*v.x + v.y*v.y) + (v.z*v.z + v.w*v.w);
    }
    #pragma unroll
    for (int off = 32; off >= 1; off >>= 1) {
        s  += __shfl_down(s, off, 64);
        ss += __shfl_down(ss, off, 64);
    }
    __shared__ float rs[4], rss[4];
    int wid = tid >> 6, lane = tid & 63;
    if (lane == 0) { rs[wid] = s; rss[wid] = ss; }
    __syncthreads();
    if (tid == 0) {
        part[c] = make_float2(rs[0] + rs[1] + rs[2] + rs[3],
                              rss[0] + rss[1] + rss[2] + rss[3]);
    }
}

// ---------------------------------------------------------------------------
// Kernel 2: prep — blocks 0..255: GN-normalize + transpose x -> Xt[n][c] bf16
//           blocks 256..267: qkvw f32->bf16;  blocks 268..271: projw f32->bf16
// ---------------------------------------------------------------------------
__global__ __launch_bounds__(256) void prep_kernel(
    const float* __restrict__ X, const float2* __restrict__ part,
    const float* __restrict__ gamma, const float* __restrict__ beta,
    const float* __restrict__ qkvw, const float* __restrict__ projw,
    unsigned short* __restrict__ Xt, unsigned short* __restrict__ Wqb,
    unsigned short* __restrict__ Wpb)
{
    int bi = blockIdx.x, tid = threadIdx.x;
    if (bi >= 256) {
        // weight conversion: 16384 elems per block
        const float* src; unsigned short* dst;
        if (bi < 268) { src = qkvw + (size_t)(bi - 256) * 16384; dst = Wqb + (size_t)(bi - 256) * 16384; }
        else          { src = projw + (size_t)(bi - 268) * 16384; dst = Wpb + (size_t)(bi - 268) * 16384; }
        #pragma unroll
        for (int i = 0; i < 16; i++) {
            float4 v = *(const float4*)(src + (size_t)tid * 4 + (size_t)i * 1024);
            short4v w;
            w[0] = (short)f2bf(v.x); w[1] = (short)f2bf(v.y);
            w[2] = (short)f2bf(v.z); w[3] = (short)f2bf(v.w);
            *(short4v*)(dst + (size_t)tid * 4 + (size_t)i * 1024) = w;
        }
        return;
    }
    // transpose tile: channels [ci*64, +64) x tokens [ni*64, +64)
    __shared__ float plds[64 * 65];
    __shared__ float gmean[8], grstd[8];
    int ci = bi >> 6, ni = bi & 63;
    if (tid < 8) {
        int g = ci * 8 + tid;     // group index
        float s = 0.f, ss = 0.f;
        #pragma unroll
        for (int k = 0; k < 8; k++) {
            float2 p = part[g * 8 + k];
            s += p.x; ss += p.y;
        }
        float mean = s * (1.f / 32768.f);
        float var  = ss * (1.f / 32768.f) - mean * mean;
        gmean[tid] = mean;
        grstd[tid] = rsqrtf(var + 1e-5f);
    }
    __syncthreads();
    #pragma unroll
    for (int i = 0; i < 4; i++) {
        int cl = (tid >> 4) + i * 16;            // 0..63 local channel
        int c  = ci * 64 + cl;
        int gl = cl >> 3;
        float scv = gamma[c] * grstd[gl];
        float tcv = beta[c] - gmean[gl] * scv;
        float4 v = *(const float4*)(X + (size_t)c * NTOK + ni * 64 + (tid & 15) * 4);
        float* row = plds + cl * 65 + (tid & 15) * 4;
        row[0] = v.x * scv + tcv; row[1] = v.y * scv + tcv;
        row[2] = v.z * scv + tcv; row[3] = v.w * scv + tcv;
    }
    __syncthreads();
    // write transposed: thread -> token row (n), 16 channels
    int nw = tid >> 2, c4 = (tid & 3) * 16;
    unsigned short tmp[16];
    #pragma unroll
    for (int i = 0; i < 16; i++) tmp[i] = f2bf(plds[(c4 + i) * 65 + nw]);
    unsigned short* dst = Xt + (size_t)(ni * 64 + nw) * CCH + ci * 64 + c4;
    *(short8*)dst       = *(short8*)&tmp[0];
    *(short8*)(dst + 8) = *(short8*)&tmp[8];
}

// ---------------------------------------------------------------------------
// Kernel 3: QKV GEMM via MFMA. D[n][o] = Xt[n][:]·Wq[o][:], direct-to-reg
// short8 frags (no LDS staging). Writes Qb[h][n][32] (xQSCALE), Kb[h][n][32],
// Vt[h][32][n] (V via same-wave LDS transpose bounce).
// ---------------------------------------------------------------------------
__global__ __launch_bounds__(256) void qkv_mfma_kernel(
    const unsigned short* __restrict__ Wqb, const unsigned short* __restrict__ Xt,
    const float* __restrict__ qkvb,
    unsigned short* __restrict__ Qb, unsigned short* __restrict__ Kbf,
    unsigned short* __restrict__ Vtb)
{
    __shared__ __align__(16) char vlds[16384];
    const int tid = threadIdx.x;
    const int wid = tid >> 6, lane = tid & 63;
    const int l31 = lane & 31, hi = lane >> 5;
    const int bo = blockIdx.x >> 5, ng = blockIdx.x & 31;
    const int o0 = bo * 32;
    const int n0 = ng * 128 + wid * 32;

    const unsigned short* ap = Xt + (size_t)(n0 + l31) * CCH + hi * 8;
    const unsigned short* bp = Wqb + (size_t)(o0 + l31) * CCH + hi * 8;

    f32x16 acc;
    #pragma unroll
    for (int i = 0; i < 16; i++) acc[i] = 0.f;
    #pragma unroll 4
    for (int ks = 0; ks < 16; ks++) {
        short8 af = *(const short8*)(ap + ks * 16);
        short8 bf = *(const short8*)(bp + ks * 16);
        acc = __builtin_amdgcn_mfma_f32_32x32x16_bf16(af, bf, acc, 0, 0, 0);
    }

    const int t3 = bo >> 3;
    const int h  = (o0 >> 5) & 7;
    const float bias = qkvb[o0 + l31];           // o = col = o0+l31

    if (t3 != 2) {
        unsigned short* dst = ((t3 == 0) ? Qb : Kbf) + (size_t)h * NTOK * HD + l31;
        const float scl = (t3 == 0) ? QSCALE : 1.0f;
        #pragma unroll
        for (int r = 0; r < 16; r++) {
            int n = n0 + CROW(r, hi);
            dst[(size_t)n * HD] = f2bf((acc[r] + bias) * scl);
        }
    } else {
        // V: stash D[n][d] to LDS (swizzled), same-wave transposed read, store Vt[h][d][n]
        char* my = vlds + wid * 4096;
        #pragma unroll
        for (int r = 0; r < 16; r++) {
            int row = CROW(r, hi);
            *(float*)(my + row * 128 + ((l31 * 4) ^ ((row & 7) << 4))) = acc[r] + bias;
        }
        unsigned short tmp[16];
        #pragma unroll
        for (int i = 0; i < 16; i++) {
            int n = hi * 16 + i;
            tmp[i] = f2bf(*(const float*)(my + n * 128 + ((l31 * 4) ^ ((n & 7) << 4))));
        }
        unsigned short* vd = Vtb + ((size_t)h * HD + l31) * NTOK + n0 + hi * 16;
        *(short8*)vd       = *(short8*)&tmp[0];
        *(short8*)(vd + 8) = *(short8*)&tmp[8];
    }
}

// ---------------------------------------------------------------------------
// Kernel 4: flash attention. 4 waves share 32 q-rows (stride-16 q so the
// combine emits the proj-ready transpose), each wave covers a 1024-key
// quarter. K frags direct global->reg (double-buffered); V LDS-staged via
// GLDS ring + counted vmcnt; no main-loop barrier. exp via v_exp_f32;
// P exchange via v_permlane32_swap (HW dir: a.hi<->b.lo, proven r4).
// Combine normalizes and writes att_t[p][c] bf16.
// ---------------------------------------------------------------------------
__global__ __launch_bounds__(256, 4) void attn_mfma_kernel(
    const unsigned short* __restrict__ Qb, const unsigned short* __restrict__ Kbf,
    const unsigned short* __restrict__ Vtb, unsigned short* __restrict__ att_t)
{
    __shared__ __align__(16) char ldsbuf[16384];   // per wave 4KB: 2-ring V (2KB each); reused as O-stash
    __shared__ float lsum[4][32];
    const int tid = threadIdx.x;
    const int wid = tid >> 6, lane = tid & 63;
    const int l31 = lane & 31, hi = lane >> 5;
    const int bid = blockIdx.x;
    const int h    = bid & 7;            // head -> XCD
    const int base = (bid >> 3) & 15;
    const int j0   = (bid >> 7) * 32;

    const unsigned short* Kh = Kbf + (size_t)h * NTOK * HD;
    const char* Vhb = (const char*)(Vtb + (size_t)h * HD * NTOK) + (size_t)wid * 2048;

    // V LDS swizzle on 16B-block index (2KB region = 128 blocks): involution,
    // flips bits [2:0] with bits [5:3]
    auto swz = [](int b) { return b ^ ((b >> 3) & 7); };
    int voff[2];
    #pragma unroll
    for (int m = 0; m < 2; m++) voff[m] = swz(l31 * 4 + m * 2 + hi) * 16;

    const int pk0 = swz(lane), pk1 = swz(lane + 64);
    const char* srcV0 = Vhb + (size_t)(pk0 >> 2) * 8192 + (pk0 & 3) * 16;   // + t*64
    const char* srcV1 = Vhb + (size_t)(pk1 >> 2) * 8192 + (pk1 & 3) * 16;
    char* myLDS = ldsbuf + wid * 4096;

#define STAGE_V(tt, bb) do { \
    char* _db = myLDS + (bb) * 2048; \
    GLDS(srcV0 + (size_t)(tt) * 64, _db); \
    GLDS(srcV1 + (size_t)(tt) * 64, _db + 1024); \
} while (0)

    // K per-lane base (this wave's quarter): key row = wid*1024 + t*32 + l31
    const unsigned short* kp = Kh + ((size_t)(wid * 1024) + l31) * HD + hi * 8;

    // Q B-frag: lane (q-col rr=l31): q = base + 16*(j0+l31)
    const unsigned short* qp = Qb + ((size_t)h * NTOK + base + 16 * (size_t)(j0 + l31)) * HD + hi * 8;
    short8 qf0 = *(const short8*)qp;
    short8 qf1 = *(const short8*)(qp + 16);

    f32x16 oacc;
    #pragma unroll
    for (int i = 0; i < 16; i++) oacc[i] = 0.f;
    const f32x16 zero = oacc;
    float l = 0.f;

    short8 kb0[2], kb1[2];
    STAGE_V(0, 0);
    kb0[0] = *(const short8*)(kp);
    kb1[0] = *(const short8*)(kp + 16);

    #pragma unroll 2
    for (int t = 0; t < 32; t++) {
        const int cur = t & 1, nxt = cur ^ 1;
        if (t < 31) {
            STAGE_V(t + 1, nxt);
            kb0[nxt] = *(const short8*)(kp + (t + 1) * 1024);
            kb1[nxt] = *(const short8*)(kp + (t + 1) * 1024 + 16);
            // 4 newest ops = tile t+1's (2 GLDS + 2 K loads); everything for t done
            asm volatile("s_waitcnt vmcnt(4)" ::: "memory");
        } else {
            asm volatile("s_waitcnt vmcnt(0)" ::: "memory");
        }

        // S^T[key][q] over hd=32 (Q pre-scaled to log2 domain)
        f32x16 s = __builtin_amdgcn_mfma_f32_32x32x16_bf16(kb0[cur], qf0, zero, 0, 0, 0);
        s = __builtin_amdgcn_mfma_f32_32x32x16_bf16(kb1[cur], qf1, s, 0, 0, 0);

        float p[16];
        #pragma unroll
        for (int r = 0; r < 16; r++) p[r] = exp2hw(s[r]);
        l += (((p[0]+p[1]) + (p[2]+p[3])) + ((p[4]+p[5]) + (p[6]+p[7])))
           + (((p[8]+p[9]) + (p[10]+p[11])) + ((p[12]+p[13]) + (p[14]+p[15])));

        const char* vb = myLDS + cur * 2048;
        short8 vf0 = *(const short8*)(vb + voff[0]);
        short8 vf1 = *(const short8*)(vb + voff[1]);

        // keys per reg r: key = (r&3) + 8*(r>>2) + 4*hi (+16 for m=1)
        #pragma unroll
        for (int m = 0; m < 2; m++) {
            const int b8 = m * 8;
            unsigned A0 = packbf2(p[b8 + 0], p[b8 + 1]);   // pk01
            unsigned A1 = packbf2(p[b8 + 2], p[b8 + 3]);   // pk23
            unsigned B0 = packbf2(p[b8 + 4], p[b8 + 5]);   // pk45
            unsigned B1 = packbf2(p[b8 + 6], p[b8 + 7]);   // pk67
            // v_permlane32_swap: A.hi <-> B.lo  =>
            //  A0 = {pk01.lo | pk45.lo} = pa[0];  B0 = {pk01.hi | pk45.hi} = pa[2]
            asm volatile("v_permlane32_swap_b32 %0, %1" : "+v"(A0), "+v"(B0));
            asm volatile("v_permlane32_swap_b32 %0, %1" : "+v"(A1), "+v"(B1));
            union { unsigned u[4]; short8 v; } pa;
            pa.u[0] = A0; pa.u[1] = A1; pa.u[2] = B0; pa.u[3] = B1;
            oacc = __builtin_amdgcn_mfma_f32_32x32x16_bf16(
                pa.v, (m == 0) ? vf0 : vf1, oacc, 0, 0, 0);
        }
    }
#undef STAGE_V

    // ---- in-block combine ----
    l += __shfl_xor(l, 32, 64);
    #pragma unroll
    for (int r = 0; r < 16; r++) {
        int row = CROW(r, hi);
        *(float*)(myLDS + row * 128 + ((l31 * 4) ^ ((row & 7) << 4))) = oacc[r];
    }
    if (lane < 32) lsum[wid][lane] = l;
    __syncthreads();

    // thread t: d = t>>3 (0..31), j4 = (t&7)*4; writes att_t[p][j0+j4..+3]
    const int d = tid >> 3, j4 = (tid & 7) * 4;
    unsigned short ob[4];
    #pragma unroll
    for (int jj = 0; jj < 4; jj++) {
        int row = j4 + jj;
        float lt = (lsum[0][row] + lsum[1][row]) + (lsum[2][row] + lsum[3][row]);
        int so = row * 128 + ((d * 4) ^ ((row & 7) << 4));
        float a = (*(const float*)(ldsbuf + so)         + *(const float*)(ldsbuf + 4096 + so))
                + (*(const float*)(ldsbuf + 8192 + so)  + *(const float*)(ldsbuf + 12288 + so));
        ob[jj] = f2bf(a / lt);
    }
    unsigned short* dst = att_t + ((size_t)(base * 256 + h * 32 + d)) * CCH + j0 + j4;
    *(short4v*)dst = *(short4v*)ob;
}

// ---------------------------------------------------------------------------
// Kernel 5: output projection via MFMA + bias + residual.
//   out[o][p] = x[o][p] + pb[o] + sum_c Wp[o][c]*att_t[p][c]
// ---------------------------------------------------------------------------
__global__ __launch_bounds__(256) void proj_mfma_kernel(
    const unsigned short* __restrict__ Wpb, const unsigned short* __restrict__ att_t,
    const float* __restrict__ X, const float* __restrict__ pb,
    float* __restrict__ out)
{
    const int tid = threadIdx.x;
    const int wid = tid >> 6, lane = tid & 63;
    const int l31 = lane & 31, hi = lane >> 5;
    const int ot = blockIdx.x >> 5, pg = blockIdx.x & 31;
    const int o0 = ot * 32;
    const int p0 = pg * 128 + wid * 32;

    const unsigned short* ap = Wpb + (size_t)(o0 + l31) * CCH + hi * 8;
    const unsigned short* bp = att_t + (size_t)(p0 + l31) * CCH + hi * 8;

    f32x16 acc;
    #pragma unroll
    for (int i = 0; i < 16; i++) acc[i] = 0.f;
    #pragma unroll 4
    for (int ks = 0; ks < 16; ks++) {
        short8 af = *(const short8*)(ap + ks * 16);
        short8 bf = *(const short8*)(bp + ks * 16);
        acc = __builtin_amdgcn_mfma_f32_32x32x16_bf16(af, bf, acc, 0, 0, 0);
    }
    #pragma unroll
    for (int r = 0; r < 16; r++) {
        int o = o0 + CROW(r, hi);
        size_t ofs = (size_t)o * NTOK + p0 + l31;
        out[ofs] = X[ofs] + pb[o] + acc[r];
    }
}

// ---------------------------------------------------------------------------
extern "C" void kernel_launch(void* const* d_in, const int* in_sizes, int n_in,
                              void* d_out, int out_size, void* d_ws, size_t ws_size,
                              hipStream_t stream)
{
    const float* x     = (const float*)d_in[0];
    const float* gamma = (const float*)d_in[1];
    const float* beta  = (const float*)d_in[2];
    const float* qkvw  = (const float*)d_in[3];
    const float* qkvb  = (const float*)d_in[4];
    const float* projw = (const float*)d_in[5];
    const float* projb = (const float*)d_in[6];
    float* out = (float*)d_out;

    char* ws = (char*)d_ws;
    const size_t MB = 1024 * 1024;
    float2* part = (float2*)ws;                                    // 2KB
    unsigned short* Xt    = (unsigned short*)(ws + 4096);          // 2MB [4096][256]
    unsigned short* Wqb   = (unsigned short*)(ws + 4096 + 2*MB);   // 384KB [768][256]
    unsigned short* Wpb   = Wqb + 768 * 256;                       // 128KB [256][256]
    unsigned short* Qb    = Wpb + 256 * 256;                       // 2MB [8][4096][32]
    unsigned short* Kbf   = Qb + HEADS * NTOK * HD;                // 2MB
    unsigned short* Vtb   = Kbf + HEADS * NTOK * HD;               // 2MB [8][32][4096]
    unsigned short* att_t = Vtb + HEADS * NTOK * HD;               // 2MB [4096][256]

    gn_part_kernel<<<256, 256, 0, stream>>>(x, part);
    prep_kernel<<<272, 256, 0, stream>>>(x, part, gamma, beta, qkvw, projw, Xt, Wqb, Wpb);
    qkv_mfma_kernel<<<768, 256, 0, stream>>>(Wqb, Xt, qkvb, Qb, Kbf, Vtb);
    attn_mfma_kernel<<<1024, 256, 0, stream>>>(Qb, Kbf, Vtb, att_t);
    proj_mfma_kernel<<<256, 256, 0, stream>>>(Wpb, att_t, x, projb, out);
}

// Round 8
// 68.955 us; speedup vs baseline: 4.2158x; 4.2158x over previous
//
#include <hip/hip_runtime.h>
#include <hip/hip_bf16.h>
#include <cstddef>
#include <cstdint>

// Shapes (hard-coded from reference): B=1, C=256, D=H=W=16 -> N=4096
// heads=8, hd=32, GROUPS=32 (8 ch/group)
#define NTOK 4096
#define CCH  256
#define HEADS 8
#define HD    32
// (1/sqrt(32)) * log2(e): scores computed directly in log2 domain
#define QSCALE 0.25503494f

typedef __attribute__((ext_vector_type(8)))  short short8;
typedef __attribute__((ext_vector_type(4)))  short short4v;
typedef __attribute__((ext_vector_type(16))) float f32x16;

__device__ __forceinline__ unsigned short f2bf(float x) {
    unsigned u = __builtin_bit_cast(unsigned, x);
    u = (u + 0x7fffu + ((u >> 16) & 1u)) >> 16;   // RNE truncate to bf16
    return (unsigned short)u;
}
// packed bf16 pair via HW cvt: low16 = bf16(a), high16 = bf16(b)
__device__ __forceinline__ unsigned packbf2(float a, float b) {
    unsigned r;
    asm("v_cvt_pk_bf16_f32 %0, %1, %2" : "=v"(r) : "v"(a), "v"(b));
    return r;
}
// hardware 2^x (1 instr; avoids libm exp2f sequence)
__device__ __forceinline__ float exp2hw(float x) {
    float r;
    asm("v_exp_f32 %0, %1" : "=v"(r) : "v"(x));
    return r;
}

// async global->LDS, 16B per lane, linear LDS dest (wave-uniform base + lane*16)
#define GLDS(gsrc, ldst) \
  __builtin_amdgcn_global_load_lds((const __attribute__((address_space(1))) unsigned int*)(const void*)(gsrc), \
                                   (__attribute__((address_space(3))) unsigned int*)(void*)(ldst), 16, 0, 0)

#define CROW(r, hi) (((r) & 3) + 8 * ((r) >> 2) + 4 * (hi))

// ---------------------------------------------------------------------------
// Kernel 1: per-channel partial sums for GroupNorm. 256 blocks = 1 per channel.
// ---------------------------------------------------------------------------
__global__ __launch_bounds__(256) void gn_part_kernel(
    const float* __restrict__ X, float2* __restrict__ part)
{
    int c = blockIdx.x, tid = threadIdx.x;
    const float4* xr = (const float4*)(X + (size_t)c * NTOK);
    float s = 0.f, ss = 0.f;
    #pragma unroll
    for (int i = 0; i < 4; i++) {
        float4 v = xr[tid + i * 256];
        s  += (v.x + v.y) + (v.z + v.w);
        ss += (v.x*v.x + v.y*v.y) + (v.z*v.z + v.w*v.w);
    }
    #pragma unroll
    for (int off = 32; off >= 1; off >>= 1) {
        s  += __shfl_down(s, off, 64);
        ss += __shfl_down(ss, off, 64);
    }
    __shared__ float rs[4], rss[4];
    int wid = tid >> 6, lane = tid & 63;
    if (lane == 0) { rs[wid] = s; rss[wid] = ss; }
    __syncthreads();
    if (tid == 0) {
        part[c] = make_float2(rs[0] + rs[1] + rs[2] + rs[3],
                              rss[0] + rss[1] + rss[2] + rss[3]);
    }
}

// ---------------------------------------------------------------------------
// Kernel 2: prep — blocks 0..255: GN-normalize + transpose x -> Xt[n][c] bf16
//           blocks 256..267: qkvw f32->bf16;  blocks 268..271: projw f32->bf16
// ---------------------------------------------------------------------------
__global__ __launch_bounds__(256) void prep_kernel(
    const float* __restrict__ X, const float2* __restrict__ part,
    const float* __restrict__ gamma, const float* __restrict__ beta,
    const float* __restrict__ qkvw, const float* __restrict__ projw,
    unsigned short* __restrict__ Xt, unsigned short* __restrict__ Wqb,
    unsigned short* __restrict__ Wpb)
{
    int bi = blockIdx.x, tid = threadIdx.x;
    if (bi >= 256) {
        const float* src; unsigned short* dst;
        if (bi < 268) { src = qkvw + (size_t)(bi - 256) * 16384; dst = Wqb + (size_t)(bi - 256) * 16384; }
        else          { src = projw + (size_t)(bi - 268) * 16384; dst = Wpb + (size_t)(bi - 268) * 16384; }
        #pragma unroll
        for (int i = 0; i < 16; i++) {
            float4 v = *(const float4*)(src + (size_t)tid * 4 + (size_t)i * 1024);
            short4v w;
            w[0] = (short)f2bf(v.x); w[1] = (short)f2bf(v.y);
            w[2] = (short)f2bf(v.z); w[3] = (short)f2bf(v.w);
            *(short4v*)(dst + (size_t)tid * 4 + (size_t)i * 1024) = w;
        }
        return;
    }
    __shared__ float plds[64 * 65];
    __shared__ float gmean[8], grstd[8];
    int ci = bi >> 6, ni = bi & 63;
    if (tid < 8) {
        int g = ci * 8 + tid;
        float s = 0.f, ss = 0.f;
        #pragma unroll
        for (int k = 0; k < 8; k++) {
            float2 p = part[g * 8 + k];
            s += p.x; ss += p.y;
        }
        float mean = s * (1.f / 32768.f);
        float var  = ss * (1.f / 32768.f) - mean * mean;
        gmean[tid] = mean;
        grstd[tid] = rsqrtf(var + 1e-5f);
    }
    __syncthreads();
    #pragma unroll
    for (int i = 0; i < 4; i++) {
        int cl = (tid >> 4) + i * 16;
        int c  = ci * 64 + cl;
        int gl = cl >> 3;
        float scv = gamma[c] * grstd[gl];
        float tcv = beta[c] - gmean[gl] * scv;
        float4 v = *(const float4*)(X + (size_t)c * NTOK + ni * 64 + (tid & 15) * 4);
        float* row = plds + cl * 65 + (tid & 15) * 4;
        row[0] = v.x * scv + tcv; row[1] = v.y * scv + tcv;
        row[2] = v.z * scv + tcv; row[3] = v.w * scv + tcv;
    }
    __syncthreads();
    int nw = tid >> 2, c4 = (tid & 3) * 16;
    unsigned short tmp[16];
    #pragma unroll
    for (int i = 0; i < 16; i++) tmp[i] = f2bf(plds[(c4 + i) * 65 + nw]);
    unsigned short* dst = Xt + (size_t)(ni * 64 + nw) * CCH + ci * 64 + c4;
    *(short8*)dst       = *(short8*)&tmp[0];
    *(short8*)(dst + 8) = *(short8*)&tmp[8];
}

// ---------------------------------------------------------------------------
// Kernel 3: QKV GEMM via MFMA, direct-to-reg frags. Writes Qb[h][n][32]
// (xQSCALE), Kb[h][n][32], Vt[h][32][n] (V via same-wave LDS transpose).
// ---------------------------------------------------------------------------
__global__ __launch_bounds__(256) void qkv_mfma_kernel(
    const unsigned short* __restrict__ Wqb, const unsigned short* __restrict__ Xt,
    const float* __restrict__ qkvb,
    unsigned short* __restrict__ Qb, unsigned short* __restrict__ Kbf,
    unsigned short* __restrict__ Vtb)
{
    __shared__ __align__(16) char vlds[16384];
    const int tid = threadIdx.x;
    const int wid = tid >> 6, lane = tid & 63;
    const int l31 = lane & 31, hi = lane >> 5;
    const int bo = blockIdx.x >> 5, ng = blockIdx.x & 31;
    const int o0 = bo * 32;
    const int n0 = ng * 128 + wid * 32;

    const unsigned short* ap = Xt + (size_t)(n0 + l31) * CCH + hi * 8;
    const unsigned short* bp = Wqb + (size_t)(o0 + l31) * CCH + hi * 8;

    f32x16 acc;
    #pragma unroll
    for (int i = 0; i < 16; i++) acc[i] = 0.f;
    #pragma unroll 4
    for (int ks = 0; ks < 16; ks++) {
        short8 af = *(const short8*)(ap + ks * 16);
        short8 bf = *(const short8*)(bp + ks * 16);
        acc = __builtin_amdgcn_mfma_f32_32x32x16_bf16(af, bf, acc, 0, 0, 0);
    }

    const int t3 = bo >> 3;
    const int h  = (o0 >> 5) & 7;
    const float bias = qkvb[o0 + l31];

    if (t3 != 2) {
        unsigned short* dst = ((t3 == 0) ? Qb : Kbf) + (size_t)h * NTOK * HD + l31;
        const float scl = (t3 == 0) ? QSCALE : 1.0f;
        #pragma unroll
        for (int r = 0; r < 16; r++) {
            int n = n0 + CROW(r, hi);
            dst[(size_t)n * HD] = f2bf((acc[r] + bias) * scl);
        }
    } else {
        char* my = vlds + wid * 4096;
        #pragma unroll
        for (int r = 0; r < 16; r++) {
            int row = CROW(r, hi);
            *(float*)(my + row * 128 + ((l31 * 4) ^ ((row & 7) << 4))) = acc[r] + bias;
        }
        unsigned short tmp[16];
        #pragma unroll
        for (int i = 0; i < 16; i++) {
            int n = hi * 16 + i;
            tmp[i] = f2bf(*(const float*)(my + n * 128 + ((l31 * 4) ^ ((n & 7) << 4))));
        }
        unsigned short* vd = Vtb + ((size_t)h * HD + l31) * NTOK + n0 + hi * 16;
        *(short8*)vd       = *(short8*)&tmp[0];
        *(short8*)(vd + 8) = *(short8*)&tmp[8];
    }
}

// ---------------------------------------------------------------------------
// Kernel 4: flash attention. R6-proven staging structure: 4 waves share 32
// q-columns (stride-16 token map), each wave covers a private 1024-key
// quarter; K+V staged via GLDS into a per-wave 2x4KB LDS ring, counted
// vmcnt(4), NO main-loop barrier. exp via v_exp_f32, P exchange via
// v_permlane32_swap (R7-verified direction). Combine writes bf16 att_t.
// ---------------------------------------------------------------------------
__global__ __launch_bounds__(256, 4) void attn_mfma_kernel(
    const unsigned short* __restrict__ Qb, const unsigned short* __restrict__ Kbf,
    const unsigned short* __restrict__ Vtb, unsigned short* __restrict__ att_t)
{
    __shared__ __align__(16) char ldsbuf[32768];   // 4 waves x (2-ring x (K 2KB | V 2KB))
    __shared__ float lsum[4][32];
    const int tid = threadIdx.x;
    const int wid = tid >> 6, lane = tid & 63;
    const int l31 = lane & 31, hi = lane >> 5;
    const int bid = blockIdx.x;
    const int h    = bid & 7;            // head -> XCD
    const int base = (bid >> 3) & 15;
    const int j0   = (bid >> 7) * 32;

    // this wave's key quarter
    const char* Khb = (const char*)(Kbf + (size_t)h * NTOK * HD) + (size_t)wid * 65536;
    const char* Vhb = (const char*)(Vtb + (size_t)h * HD * NTOK) + (size_t)wid * 2048;

    // 16B-block swizzle (involution: flips bits[1:0] with bits[3:2])
    auto swz = [](int b) { return b ^ ((b >> 2) & 3); };

    int koff[2], voff[2];
    #pragma unroll
    for (int x = 0; x < 2; x++) {
        int so = swz(l31 * 4 + x * 2 + hi) * 16;
        koff[x] = so;
        voff[x] = 2048 + so;
    }

    const int pk0 = swz(lane), pk1 = swz(lane + 64);
    const char* srcK0 = Khb + pk0 * 16;                                   // +t*2048
    const char* srcK1 = Khb + pk1 * 16;
    const char* srcV0 = Vhb + (size_t)(pk0 >> 2) * 8192 + (pk0 & 3) * 16; // +t*64
    const char* srcV1 = Vhb + (size_t)(pk1 >> 2) * 8192 + (pk1 & 3) * 16;
    char* myLDS = ldsbuf + wid * 8192;

#define STAGE(tt, bb) do { \
    char* _db = myLDS + (bb) * 4096; \
    GLDS(srcK0 + (size_t)(tt) * 2048, _db); \
    GLDS(srcK1 + (size_t)(tt) * 2048, _db + 1024); \
    GLDS(srcV0 + (size_t)(tt) * 64,   _db + 2048); \
    GLDS(srcV1 + (size_t)(tt) * 64,   _db + 3072); \
} while (0)

    // Q B-frag: q-col l31 <-> token q = base + 16*(j0+l31)
    const unsigned short* qp = Qb + ((size_t)h * NTOK + base + 16 * (size_t)(j0 + l31)) * HD + hi * 8;
    short8 qf0 = *(const short8*)qp;
    short8 qf1 = *(const short8*)(qp + 16);

    f32x16 oacc;
    #pragma unroll
    for (int i = 0; i < 16; i++) oacc[i] = 0.f;
    const f32x16 zero = oacc;
    float l = 0.f;

    STAGE(0, 0);

    #pragma unroll 1
    for (int t = 0; t < 32; t++) {
        if (t < 31) {
            STAGE(t + 1, (t + 1) & 1);
            asm volatile("s_waitcnt vmcnt(4)" ::: "memory");  // tile t landed
        } else {
            asm volatile("s_waitcnt vmcnt(0)" ::: "memory");
        }
        const char* kb = myLDS + (t & 1) * 4096;
        short8 kf0 = *(const short8*)(kb + koff[0]);
        short8 kf1 = *(const short8*)(kb + koff[1]);
        // S^T[key][q] over hd=32 (Q pre-scaled to log2 domain)
        f32x16 s = __builtin_amdgcn_mfma_f32_32x32x16_bf16(kf0, qf0, zero, 0, 0, 0);
        s = __builtin_amdgcn_mfma_f32_32x32x16_bf16(kf1, qf1, s, 0, 0, 0);

        float p[16];
        #pragma unroll
        for (int r = 0; r < 16; r++) p[r] = exp2hw(s[r]);
        l += (((p[0]+p[1]) + (p[2]+p[3])) + ((p[4]+p[5]) + (p[6]+p[7])))
           + (((p[8]+p[9]) + (p[10]+p[11])) + ((p[12]+p[13]) + (p[14]+p[15])));

        short8 vf0 = *(const short8*)(kb + voff[0]);
        short8 vf1 = *(const short8*)(kb + voff[1]);

        // keys per reg r: key = (r&3) + 8*(r>>2) + 4*hi (+16 for m=1)
        #pragma unroll
        for (int m = 0; m < 2; m++) {
            const int b8 = m * 8;
            unsigned A0 = packbf2(p[b8 + 0], p[b8 + 1]);   // pk01
            unsigned A1 = packbf2(p[b8 + 2], p[b8 + 3]);   // pk23
            unsigned B0 = packbf2(p[b8 + 4], p[b8 + 5]);   // pk45
            unsigned B1 = packbf2(p[b8 + 6], p[b8 + 7]);   // pk67
            // v_permlane32_swap (HW: A.hi <-> B.lo across lane halves):
            //   A0 -> pa[0], B0 -> pa[2]; A1 -> pa[1], B1 -> pa[3]
            asm volatile("v_permlane32_swap_b32 %0, %1" : "+v"(A0), "+v"(B0));
            asm volatile("v_permlane32_swap_b32 %0, %1" : "+v"(A1), "+v"(B1));
            union { unsigned u[4]; short8 v; } pa;
            pa.u[0] = A0; pa.u[1] = A1; pa.u[2] = B0; pa.u[3] = B1;
            oacc = __builtin_amdgcn_mfma_f32_32x32x16_bf16(
                pa.v, (m == 0) ? vf0 : vf1, oacc, 0, 0, 0);
        }
    }
#undef STAGE

    // ---- in-block combine ----
    l += __shfl_xor(l, 32, 64);   // full 32-key partial denominator for q = l31
    // stash O-partial into own ring0 (dead: tile 31 read ring1).
    // oacc[r]: j-row = CROW(r,hi), channel col = l31
    #pragma unroll
    for (int r = 0; r < 16; r++) {
        int row = CROW(r, hi);
        *(float*)(myLDS + row * 128 + ((l31 * 4) ^ ((row & 7) << 4))) = oacc[r];
    }
    if (lane < 32) lsum[wid][lane] = l;
    __syncthreads();

    // thread: d = tid>>3 (channel 0..31), j4 = (tid&7)*4 (j-rows)
    const int d = tid >> 3, j4 = (tid & 7) * 4;
    unsigned short ob[4];
    #pragma unroll
    for (int jj = 0; jj < 4; jj++) {
        int row = j4 + jj;
        float lt = (lsum[0][row] + lsum[1][row]) + (lsum[2][row] + lsum[3][row]);
        int so = row * 128 + ((d * 4) ^ ((row & 7) << 4));
        float a = (*(const float*)(ldsbuf + so)          + *(const float*)(ldsbuf + 8192 + so))
                + (*(const float*)(ldsbuf + 16384 + so)  + *(const float*)(ldsbuf + 24576 + so));
        ob[jj] = f2bf(a / lt);
    }
    // att_t[p][c2] with p = base*256 + h*32 + d, c2 = j0+j4..+3
    unsigned short* dst = att_t + ((size_t)(base * 256 + h * 32 + d)) * CCH + j0 + j4;
    *(short4v*)dst = *(short4v*)ob;
}

// ---------------------------------------------------------------------------
// Kernel 5: output projection via MFMA + bias + residual.
// ---------------------------------------------------------------------------
__global__ __launch_bounds__(256) void proj_mfma_kernel(
    const unsigned short* __restrict__ Wpb, const unsigned short* __restrict__ att_t,
    const float* __restrict__ X, const float* __restrict__ pb,
    float* __restrict__ out)
{
    const int tid = threadIdx.x;
    const int wid = tid >> 6, lane = tid & 63;
    const int l31 = lane & 31, hi = lane >> 5;
    const int ot = blockIdx.x >> 5, pg = blockIdx.x & 31;
    const int o0 = ot * 32;
    const int p0 = pg * 128 + wid * 32;

    const unsigned short* ap = Wpb + (size_t)(o0 + l31) * CCH + hi * 8;
    const unsigned short* bp = att_t + (size_t)(p0 + l31) * CCH + hi * 8;

    f32x16 acc;
    #pragma unroll
    for (int i = 0; i < 16; i++) acc[i] = 0.f;
    #pragma unroll 4
    for (int ks = 0; ks < 16; ks++) {
        short8 af = *(const short8*)(ap + ks * 16);
        short8 bf = *(const short8*)(bp + ks * 16);
        acc = __builtin_amdgcn_mfma_f32_32x32x16_bf16(af, bf, acc, 0, 0, 0);
    }
    #pragma unroll
    for (int r = 0; r < 16; r++) {
        int o = o0 + CROW(r, hi);
        size_t ofs = (size_t)o * NTOK + p0 + l31;
        out[ofs] = X[ofs] + pb[o] + acc[r];
    }
}

// ---------------------------------------------------------------------------
extern "C" void kernel_launch(void* const* d_in, const int* in_sizes, int n_in,
                              void* d_out, int out_size, void* d_ws, size_t ws_size,
                              hipStream_t stream)
{
    const float* x     = (const float*)d_in[0];
    const float* gamma = (const float*)d_in[1];
    const float* beta  = (const float*)d_in[2];
    const float* qkvw  = (const float*)d_in[3];
    const float* qkvb  = (const float*)d_in[4];
    const float* projw = (const float*)d_in[5];
    const float* projb = (const float*)d_in[6];
    float* out = (float*)d_out;

    char* ws = (char*)d_ws;
    const size_t MB = 1024 * 1024;
    float2* part = (float2*)ws;                                    // 2KB
    unsigned short* Xt    = (unsigned short*)(ws + 4096);          // 2MB [4096][256]
    unsigned short* Wqb   = (unsigned short*)(ws + 4096 + 2*MB);   // 384KB [768][256]
    unsigned short* Wpb   = Wqb + 768 * 256;                       // 128KB [256][256]
    unsigned short* Qb    = Wpb + 256 * 256;                       // 2MB [8][4096][32]
    unsigned short* Kbf   = Qb + HEADS * NTOK * HD;                // 2MB
    unsigned short* Vtb   = Kbf + HEADS * NTOK * HD;               // 2MB [8][32][4096]
    unsigned short* att_t = Vtb + HEADS * NTOK * HD;               // 2MB [4096][256]

    gn_part_kernel<<<256, 256, 0, stream>>>(x, part);
    prep_kernel<<<272, 256, 0, stream>>>(x, part, gamma, beta, qkvw, projw, Xt, Wqb, Wpb);
    qkv_mfma_kernel<<<768, 256, 0, stream>>>(Wqb, Xt, qkvb, Qb, Kbf, Vtb);
    attn_mfma_kernel<<<1024, 256, 0, stream>>>(Qb, Kbf, Vtb, att_t);
    proj_mfma_kernel<<<256, 256, 0, stream>>>(Wpb, att_t, x, projb, out);
}

// Round 9
// 66.554 us; speedup vs baseline: 4.3679x; 1.0361x over previous
//
#include <hip/hip_runtime.h>
#include <hip/hip_bf16.h>
#include <cstddef>
#include <cstdint>

// Shapes (hard-coded from reference): B=1, C=256, D=H=W=16 -> N=4096
// heads=8, hd=32, GROUPS=32 (8 ch/group)
#define NTOK 4096
#define CCH  256
#define HEADS 8
#define HD    32
// (1/sqrt(32)) * log2(e): scores computed directly in log2 domain
#define QSCALE 0.25503494f

typedef __attribute__((ext_vector_type(8)))  short short8;
typedef __attribute__((ext_vector_type(4)))  short short4v;
typedef __attribute__((ext_vector_type(16))) float f32x16;

__device__ __forceinline__ unsigned short f2bf(float x) {
    unsigned u = __builtin_bit_cast(unsigned, x);
    u = (u + 0x7fffu + ((u >> 16) & 1u)) >> 16;   // RNE truncate to bf16
    return (unsigned short)u;
}
// packed bf16 pair via HW cvt: low16 = bf16(a), high16 = bf16(b)
__device__ __forceinline__ unsigned packbf2(float a, float b) {
    unsigned r;
    asm("v_cvt_pk_bf16_f32 %0, %1, %2" : "=v"(r) : "v"(a), "v"(b));
    return r;
}
// hardware 2^x (1 instr; avoids libm exp2f sequence)
__device__ __forceinline__ float exp2hw(float x) {
    float r;
    asm("v_exp_f32 %0, %1" : "=v"(r) : "v"(x));
    return r;
}

// async global->LDS, 16B per lane, linear LDS dest (wave-uniform base + lane*16)
#define GLDS(gsrc, ldst) \
  __builtin_amdgcn_global_load_lds((const __attribute__((address_space(1))) unsigned int*)(const void*)(gsrc), \
                                   (__attribute__((address_space(3))) unsigned int*)(void*)(ldst), 16, 0, 0)

#define CROW(r, hi) (((r) & 3) + 8 * ((r) >> 2) + 4 * (hi))

// ---------------------------------------------------------------------------
// Kernel 1: per-channel partial sums for GroupNorm. 256 blocks = 1 per channel.
// ---------------------------------------------------------------------------
__global__ __launch_bounds__(256) void gn_part_kernel(
    const float* __restrict__ X, float2* __restrict__ part)
{
    int c = blockIdx.x, tid = threadIdx.x;
    const float4* xr = (const float4*)(X + (size_t)c * NTOK);
    float s = 0.f, ss = 0.f;
    #pragma unroll
    for (int i = 0; i < 4; i++) {
        float4 v = xr[tid + i * 256];
        s  += (v.x + v.y) + (v.z + v.w);
        ss += (v.x*v.x + v.y*v.y) + (v.z*v.z + v.w*v.w);
    }
    #pragma unroll
    for (int off = 32; off >= 1; off >>= 1) {
        s  += __shfl_down(s, off, 64);
        ss += __shfl_down(ss, off, 64);
    }
    __shared__ float rs[4], rss[4];
    int wid = tid >> 6, lane = tid & 63;
    if (lane == 0) { rs[wid] = s; rss[wid] = ss; }
    __syncthreads();
    if (tid == 0) {
        part[c] = make_float2(rs[0] + rs[1] + rs[2] + rs[3],
                              rss[0] + rss[1] + rss[2] + rss[3]);
    }
}

// ---------------------------------------------------------------------------
// Kernel 2: prep — blocks 0..255: GN-normalize + transpose x -> Xt[n][c] bf16
//           blocks 256..267: qkvw f32->bf16;  blocks 268..271: projw f32->bf16
// ---------------------------------------------------------------------------
__global__ __launch_bounds__(256) void prep_kernel(
    const float* __restrict__ X, const float2* __restrict__ part,
    const float* __restrict__ gamma, const float* __restrict__ beta,
    const float* __restrict__ qkvw, const float* __restrict__ projw,
    unsigned short* __restrict__ Xt, unsigned short* __restrict__ Wqb,
    unsigned short* __restrict__ Wpb)
{
    int bi = blockIdx.x, tid = threadIdx.x;
    if (bi >= 256) {
        const float* src; unsigned short* dst;
        if (bi < 268) { src = qkvw + (size_t)(bi - 256) * 16384; dst = Wqb + (size_t)(bi - 256) * 16384; }
        else          { src = projw + (size_t)(bi - 268) * 16384; dst = Wpb + (size_t)(bi - 268) * 16384; }
        #pragma unroll
        for (int i = 0; i < 16; i++) {
            float4 v = *(const float4*)(src + (size_t)tid * 4 + (size_t)i * 1024);
            short4v w;
            w[0] = (short)f2bf(v.x); w[1] = (short)f2bf(v.y);
            w[2] = (short)f2bf(v.z); w[3] = (short)f2bf(v.w);
            *(short4v*)(dst + (size_t)tid * 4 + (size_t)i * 1024) = w;
        }
        return;
    }
    __shared__ float plds[64 * 65];
    __shared__ float gmean[8], grstd[8];
    int ci = bi >> 6, ni = bi & 63;
    if (tid < 8) {
        int g = ci * 8 + tid;
        float s = 0.f, ss = 0.f;
        #pragma unroll
        for (int k = 0; k < 8; k++) {
            float2 p = part[g * 8 + k];
            s += p.x; ss += p.y;
        }
        float mean = s * (1.f / 32768.f);
        float var  = ss * (1.f / 32768.f) - mean * mean;
        gmean[tid] = mean;
        grstd[tid] = rsqrtf(var + 1e-5f);
    }
    __syncthreads();
    #pragma unroll
    for (int i = 0; i < 4; i++) {
        int cl = (tid >> 4) + i * 16;
        int c  = ci * 64 + cl;
        int gl = cl >> 3;
        float scv = gamma[c] * grstd[gl];
        float tcv = beta[c] - gmean[gl] * scv;
        float4 v = *(const float4*)(X + (size_t)c * NTOK + ni * 64 + (tid & 15) * 4);
        float* row = plds + cl * 65 + (tid & 15) * 4;
        row[0] = v.x * scv + tcv; row[1] = v.y * scv + tcv;
        row[2] = v.z * scv + tcv; row[3] = v.w * scv + tcv;
    }
    __syncthreads();
    int nw = tid >> 2, c4 = (tid & 3) * 16;
    unsigned short tmp[16];
    #pragma unroll
    for (int i = 0; i < 16; i++) tmp[i] = f2bf(plds[(c4 + i) * 65 + nw]);
    unsigned short* dst = Xt + (size_t)(ni * 64 + nw) * CCH + ci * 64 + c4;
    *(short8*)dst       = *(short8*)&tmp[0];
    *(short8*)(dst + 8) = *(short8*)&tmp[8];
}

// ---------------------------------------------------------------------------
// Kernel 3: QKV GEMM via MFMA, direct-to-reg frags. Writes Qb[h][n][32]
// (xQSCALE), Kb[h][n][32], Vt[h][32][n] (V via same-wave LDS transpose).
// ---------------------------------------------------------------------------
__global__ __launch_bounds__(256) void qkv_mfma_kernel(
    const unsigned short* __restrict__ Wqb, const unsigned short* __restrict__ Xt,
    const float* __restrict__ qkvb,
    unsigned short* __restrict__ Qb, unsigned short* __restrict__ Kbf,
    unsigned short* __restrict__ Vtb)
{
    __shared__ __align__(16) char vlds[16384];
    const int tid = threadIdx.x;
    const int wid = tid >> 6, lane = tid & 63;
    const int l31 = lane & 31, hi = lane >> 5;
    const int bo = blockIdx.x >> 5, ng = blockIdx.x & 31;
    const int o0 = bo * 32;
    const int n0 = ng * 128 + wid * 32;

    const unsigned short* ap = Xt + (size_t)(n0 + l31) * CCH + hi * 8;
    const unsigned short* bp = Wqb + (size_t)(o0 + l31) * CCH + hi * 8;

    f32x16 acc;
    #pragma unroll
    for (int i = 0; i < 16; i++) acc[i] = 0.f;
    #pragma unroll 4
    for (int ks = 0; ks < 16; ks++) {
        short8 af = *(const short8*)(ap + ks * 16);
        short8 bf = *(const short8*)(bp + ks * 16);
        acc = __builtin_amdgcn_mfma_f32_32x32x16_bf16(af, bf, acc, 0, 0, 0);
    }

    const int t3 = bo >> 3;
    const int h  = (o0 >> 5) & 7;
    const float bias = qkvb[o0 + l31];

    if (t3 != 2) {
        unsigned short* dst = ((t3 == 0) ? Qb : Kbf) + (size_t)h * NTOK * HD + l31;
        const float scl = (t3 == 0) ? QSCALE : 1.0f;
        #pragma unroll
        for (int r = 0; r < 16; r++) {
            int n = n0 + CROW(r, hi);
            dst[(size_t)n * HD] = f2bf((acc[r] + bias) * scl);
        }
    } else {
        char* my = vlds + wid * 4096;
        #pragma unroll
        for (int r = 0; r < 16; r++) {
            int row = CROW(r, hi);
            *(float*)(my + row * 128 + ((l31 * 4) ^ ((row & 7) << 4))) = acc[r] + bias;
        }
        unsigned short tmp[16];
        #pragma unroll
        for (int i = 0; i < 16; i++) {
            int n = hi * 16 + i;
            tmp[i] = f2bf(*(const float*)(my + n * 128 + ((l31 * 4) ^ ((n & 7) << 4))));
        }
        unsigned short* vd = Vtb + ((size_t)h * HD + l31) * NTOK + n0 + hi * 16;
        *(short8*)vd       = *(short8*)&tmp[0];
        *(short8*)(vd + 8) = *(short8*)&tmp[8];
    }
}

// ---------------------------------------------------------------------------
// Kernel 4: flash attention. Block = 4 waves, covers 64 q-columns (2 Q-frags
// per wave); wave owns a private 1024-key quarter -> KV L2 traffic halved vs
// 32q blocks. K+V staged via GLDS into a per-wave ring of FOUR 4KB buffers
// (3 tiles prefetched, vmcnt(8)); NO main-loop barrier.
// LDS layout: rotated 16B blocks (phys = row + 32*e) -> bank slot = l31%8,
// 2 lanes/slot per 16-lane phase = conflict-free b128 reads.
// exp via v_exp_f32; P exchange via v_permlane32_swap. Combine -> bf16 att_t.
// ---------------------------------------------------------------------------
__global__ __launch_bounds__(256, 2) void attn_mfma_kernel(
    const unsigned short* __restrict__ Qb, const unsigned short* __restrict__ Kbf,
    const unsigned short* __restrict__ Vtb, unsigned short* __restrict__ att_t)
{
    __shared__ __align__(16) char ldsbuf[65536];   // 4 waves x (ring4 x (K 2KB | V 2KB))
    __shared__ float lsum[4][64];
    const int tid = threadIdx.x;
    const int wid = tid >> 6, lane = tid & 63;
    const int l31 = lane & 31, hi = lane >> 5;
    const int bid = blockIdx.x;          // 512 blocks
    const int h    = bid & 7;            // head -> XCD (bid%8)
    const int g    = bid >> 3;           // 0..63
    const int base = g & 15;
    const int j0   = (g >> 4) * 64;      // 0,64,128,192

    // this wave's key quarter
    const char* Khb = (const char*)(Kbf + (size_t)h * NTOK * HD) + (size_t)wid * 65536;
    const char* Vhb = (const char*)(Vtb + (size_t)h * HD * NTOK) + (size_t)wid * 2048;

    // rotated staging sources: phys block p = row + 32*e  (row=p&31, e=p>>5)
    // GLDS pair covers p = lane and p = lane+64.
    // K tile (2KB = [32 keys][64B]): src = key*64 + e*16   (+ t*2048)
    // V tile (rows of V^T [d][4096keys]): src = d*8192 + e*16 (+ t*64)
    const char* srcK0 = Khb + l31 * 64 + hi * 16;            // p=lane:    e=hi
    const char* srcK1 = Khb + l31 * 64 + 32 + hi * 16;       // p=lane+64: e=2+hi
    const char* srcV0 = Vhb + (size_t)l31 * 8192 + hi * 16;
    const char* srcV1 = Vhb + (size_t)l31 * 8192 + 32 + hi * 16;
    char* myLDS = ldsbuf + wid * 16384;

#define STAGE(tt, bb) do { \
    char* _db = myLDS + (bb) * 4096; \
    GLDS(srcK0 + (size_t)(tt) * 2048, _db); \
    GLDS(srcK1 + (size_t)(tt) * 2048, _db + 1024); \
    GLDS(srcV0 + (size_t)(tt) * 64,   _db + 2048); \
    GLDS(srcV1 + (size_t)(tt) * 64,   _db + 3072); \
} while (0)

    // read offsets: frag block = l31 + 32*e -> byte = l31*16 + e*512
    const int koff0 = l31 * 16 + hi * 512;            // e = hi
    const int koff1 = l31 * 16 + 1024 + hi * 512;     // e = 2+hi
    const int voff0 = 2048 + koff0;
    const int voff1 = 2048 + koff1;

    // Q frags: q-col j (A: j=l31, B: j=32+l31); token = base + 16*(j0+j)
    const unsigned short* qpA = Qb + ((size_t)h * NTOK + base + 16 * (size_t)(j0 + l31)) * HD + hi * 8;
    const unsigned short* qpB = qpA + (size_t)32 * 16 * HD;
    short8 qfA0 = *(const short8*)qpA;
    short8 qfA1 = *(const short8*)(qpA + 16);
    short8 qfB0 = *(const short8*)qpB;
    short8 qfB1 = *(const short8*)(qpB + 16);

    f32x16 oaccA, oaccB;
    #pragma unroll
    for (int i = 0; i < 16; i++) { oaccA[i] = 0.f; oaccB[i] = 0.f; }
    const f32x16 zero = oaccA;
    float lA = 0.f, lB = 0.f;

    STAGE(0, 0);
    STAGE(1, 1);
    STAGE(2, 2);

    #pragma unroll 1
    for (int t = 0; t < 32; t++) {
        // 12 loads outstanding (groups t, t+1, t+2); retire group t.
        asm volatile("s_waitcnt vmcnt(8)" ::: "memory");
        const int ts = (t + 3 < 32) ? (t + 3) : 31;
        STAGE(ts, (t + 3) & 3);    // buffer (t+3)&3 last read at iter t-1 (done)

        const char* kb = myLDS + (t & 3) * 4096;
        short8 kf0 = *(const short8*)(kb + koff0);
        short8 kf1 = *(const short8*)(kb + koff1);

        // two independent S^T chains (Q pre-scaled to log2 domain)
        f32x16 sA = __builtin_amdgcn_mfma_f32_32x32x16_bf16(kf0, qfA0, zero, 0, 0, 0);
        f32x16 sB = __builtin_amdgcn_mfma_f32_32x32x16_bf16(kf0, qfB0, zero, 0, 0, 0);
        sA = __builtin_amdgcn_mfma_f32_32x32x16_bf16(kf1, qfA1, sA, 0, 0, 0);
        sB = __builtin_amdgcn_mfma_f32_32x32x16_bf16(kf1, qfB1, sB, 0, 0, 0);

        short8 vf0 = *(const short8*)(kb + voff0);
        short8 vf1 = *(const short8*)(kb + voff1);

        float pA[16], pB[16];
        #pragma unroll
        for (int r = 0; r < 16; r++) pA[r] = exp2hw(sA[r]);
        #pragma unroll
        for (int r = 0; r < 16; r++) pB[r] = exp2hw(sB[r]);
        lA += (((pA[0]+pA[1]) + (pA[2]+pA[3])) + ((pA[4]+pA[5]) + (pA[6]+pA[7])))
            + (((pA[8]+pA[9]) + (pA[10]+pA[11])) + ((pA[12]+pA[13]) + (pA[14]+pA[15])));
        lB += (((pB[0]+pB[1]) + (pB[2]+pB[3])) + ((pB[4]+pB[5]) + (pB[6]+pB[7])))
            + (((pB[8]+pB[9]) + (pB[10]+pB[11])) + ((pB[12]+pB[13]) + (pB[14]+pB[15])));

        // keys per reg r: key = (r&3) + 8*(r>>2) + 4*hi (+16 for m=1)
        #pragma unroll
        for (int m = 0; m < 2; m++) {
            const int b8 = m * 8;
            unsigned A0 = packbf2(pA[b8 + 0], pA[b8 + 1]);
            unsigned A1 = packbf2(pA[b8 + 2], pA[b8 + 3]);
            unsigned B0 = packbf2(pA[b8 + 4], pA[b8 + 5]);
            unsigned B1 = packbf2(pA[b8 + 6], pA[b8 + 7]);
            asm volatile("v_permlane32_swap_b32 %0, %1" : "+v"(A0), "+v"(B0));
            asm volatile("v_permlane32_swap_b32 %0, %1" : "+v"(A1), "+v"(B1));
            union { unsigned u[4]; short8 v; } pa;
            pa.u[0] = A0; pa.u[1] = A1; pa.u[2] = B0; pa.u[3] = B1;
            oaccA = __builtin_amdgcn_mfma_f32_32x32x16_bf16(
                pa.v, (m == 0) ? vf0 : vf1, oaccA, 0, 0, 0);
        }
        #pragma unroll
        for (int m = 0; m < 2; m++) {
            const int b8 = m * 8;
            unsigned A0 = packbf2(pB[b8 + 0], pB[b8 + 1]);
            unsigned A1 = packbf2(pB[b8 + 2], pB[b8 + 3]);
            unsigned B0 = packbf2(pB[b8 + 4], pB[b8 + 5]);
            unsigned B1 = packbf2(pB[b8 + 6], pB[b8 + 7]);
            asm volatile("v_permlane32_swap_b32 %0, %1" : "+v"(A0), "+v"(B0));
            asm volatile("v_permlane32_swap_b32 %0, %1" : "+v"(A1), "+v"(B1));
            union { unsigned u[4]; short8 v; } pa;
            pa.u[0] = A0; pa.u[1] = A1; pa.u[2] = B0; pa.u[3] = B1;
            oaccB = __builtin_amdgcn_mfma_f32_32x32x16_bf16(
                pa.v, (m == 0) ? vf0 : vf1, oaccB, 0, 0, 0);
        }
    }
#undef STAGE

    // ---- in-block combine ----
    lA += __shfl_xor(lA, 32, 64);
    lB += __shfl_xor(lB, 32, 64);
    // stash O-partials: all 4 ring buffers are dead (same-wave reads done).
    // layout: [q row 0..63][32 d] f32, row stride 148B (bank shift 5/row).
    char* st = myLDS;
    #pragma unroll
    for (int r = 0; r < 16; r++) {
        int rowA = CROW(r, hi);
        *(float*)(st + rowA * 148 + l31 * 4) = oaccA[r];
        *(float*)(st + (rowA + 32) * 148 + l31 * 4) = oaccB[r];
    }
    if (lane < 32) { lsum[wid][l31] = lA; lsum[wid][32 + l31] = lB; }
    __syncthreads();

    // thread: d = tid>>3 (0..31), q8 = (tid&7)*8 -> one short8 row-store
    const int d = tid >> 3, q8 = (tid & 7) * 8;
    unsigned short ob[8];
    #pragma unroll
    for (int i = 0; i < 8; i++) {
        int q = q8 + i;
        float lt = (lsum[0][q] + lsum[1][q]) + (lsum[2][q] + lsum[3][q]);
        int so = q * 148 + d * 4;
        float a = (*(const float*)(ldsbuf + so)          + *(const float*)(ldsbuf + 16384 + so))
                + (*(const float*)(ldsbuf + 32768 + so)  + *(const float*)(ldsbuf + 49152 + so));
        ob[i] = f2bf(a / lt);
    }
    // att_t[p][c]: p = base*256 + h*32 + d, c = j0 + q8 .. +7
    unsigned short* dst = att_t + (size_t)(base * 256 + h * 32 + d) * CCH + j0 + q8;
    *(short8*)dst = *(short8*)ob;
}

// ---------------------------------------------------------------------------
// Kernel 5: output projection via MFMA + bias + residual.
// ---------------------------------------------------------------------------
__global__ __launch_bounds__(256) void proj_mfma_kernel(
    const unsigned short* __restrict__ Wpb, const unsigned short* __restrict__ att_t,
    const float* __restrict__ X, const float* __restrict__ pb,
    float* __restrict__ out)
{
    const int tid = threadIdx.x;
    const int wid = tid >> 6, lane = tid & 63;
    const int l31 = lane & 31, hi = lane >> 5;
    const int ot = blockIdx.x >> 5, pg = blockIdx.x & 31;
    const int o0 = ot * 32;
    const int p0 = pg * 128 + wid * 32;

    const unsigned short* ap = Wpb + (size_t)(o0 + l31) * CCH + hi * 8;
    const unsigned short* bp = att_t + (size_t)(p0 + l31) * CCH + hi * 8;

    f32x16 acc;
    #pragma unroll
    for (int i = 0; i < 16; i++) acc[i] = 0.f;
    #pragma unroll 4
    for (int ks = 0; ks < 16; ks++) {
        short8 af = *(const short8*)(ap + ks * 16);
        short8 bf = *(const short8*)(bp + ks * 16);
        acc = __builtin_amdgcn_mfma_f32_32x32x16_bf16(af, bf, acc, 0, 0, 0);
    }
    #pragma unroll
    for (int r = 0; r < 16; r++) {
        int o = o0 + CROW(r, hi);
        size_t ofs = (size_t)o * NTOK + p0 + l31;
        out[ofs] = X[ofs] + pb[o] + acc[r];
    }
}

// ---------------------------------------------------------------------------
extern "C" void kernel_launch(void* const* d_in, const int* in_sizes, int n_in,
                              void* d_out, int out_size, void* d_ws, size_t ws_size,
                              hipStream_t stream)
{
    const float* x     = (const float*)d_in[0];
    const float* gamma = (const float*)d_in[1];
    const float* beta  = (const float*)d_in[2];
    const float* qkvw  = (const float*)d_in[3];
    const float* qkvb  = (const float*)d_in[4];
    const float* projw = (const float*)d_in[5];
    const float* projb = (const float*)d_in[6];
    float* out = (float*)d_out;

    char* ws = (char*)d_ws;
    const size_t MB = 1024 * 1024;
    float2* part = (float2*)ws;                                    // 2KB
    unsigned short* Xt    = (unsigned short*)(ws + 4096);          // 2MB [4096][256]
    unsigned short* Wqb   = (unsigned short*)(ws + 4096 + 2*MB);   // 384KB [768][256]
    unsigned short* Wpb   = Wqb + 768 * 256;                       // 128KB [256][256]
    unsigned short* Qb    = Wpb + 256 * 256;                       // 2MB [8][4096][32]
    unsigned short* Kbf   = Qb + HEADS * NTOK * HD;                // 2MB
    unsigned short* Vtb   = Kbf + HEADS * NTOK * HD;               // 2MB [8][32][4096]
    unsigned short* att_t = Vtb + HEADS * NTOK * HD;               // 2MB [4096][256]

    gn_part_kernel<<<256, 256, 0, stream>>>(x, part);
    prep_kernel<<<272, 256, 0, stream>>>(x, part, gamma, beta, qkvw, projw, Xt, Wqb, Wpb);
    qkv_mfma_kernel<<<768, 256, 0, stream>>>(Wqb, Xt, qkvb, Qb, Kbf, Vtb);
    attn_mfma_kernel<<<512, 256, 0, stream>>>(Qb, Kbf, Vtb, att_t);
    proj_mfma_kernel<<<256, 256, 0, stream>>>(Wpb, att_t, x, projb, out);
}

// Round 10
// 62.591 us; speedup vs baseline: 4.6445x; 1.0633x over previous
//
#include <hip/hip_runtime.h>
#include <hip/hip_bf16.h>
#include <cstddef>
#include <cstdint>

// Shapes (hard-coded from reference): B=1, C=256, D=H=W=16 -> N=4096
// heads=8, hd=32, GROUPS=32 (8 ch/group)
#define NTOK 4096
#define CCH  256
#define HEADS 8
#define HD    32
// (1/sqrt(32)) * log2(e): scores computed directly in log2 domain
#define QSCALE 0.25503494f

typedef __attribute__((ext_vector_type(8)))  short short8;
typedef __attribute__((ext_vector_type(4)))  short short4v;
typedef __attribute__((ext_vector_type(16))) float f32x16;

__device__ __forceinline__ unsigned short f2bf(float x) {
    unsigned u = __builtin_bit_cast(unsigned, x);
    u = (u + 0x7fffu + ((u >> 16) & 1u)) >> 16;   // RNE truncate to bf16
    return (unsigned short)u;
}
// packed bf16 pair via HW cvt: low16 = bf16(a), high16 = bf16(b)
__device__ __forceinline__ unsigned packbf2(float a, float b) {
    unsigned r;
    asm("v_cvt_pk_bf16_f32 %0, %1, %2" : "=v"(r) : "v"(a), "v"(b));
    return r;
}
// hardware 2^x (1 instr; avoids libm exp2f sequence)
__device__ __forceinline__ float exp2hw(float x) {
    float r;
    asm("v_exp_f32 %0, %1" : "=v"(r) : "v"(x));
    return r;
}

#define CROW(r, hi) (((r) & 3) + 8 * ((r) >> 2) + 4 * (hi))

// ---------------------------------------------------------------------------
// Kernel 1: per-channel partial sums for GroupNorm. 256 blocks = 1 per channel.
// ---------------------------------------------------------------------------
__global__ __launch_bounds__(256) void gn_part_kernel(
    const float* __restrict__ X, float2* __restrict__ part)
{
    int c = blockIdx.x, tid = threadIdx.x;
    const float4* xr = (const float4*)(X + (size_t)c * NTOK);
    float s = 0.f, ss = 0.f;
    #pragma unroll
    for (int i = 0; i < 4; i++) {
        float4 v = xr[tid + i * 256];
        s  += (v.x + v.y) + (v.z + v.w);
        ss += (v.x*v.x + v.y*v.y) + (v.z*v.z + v.w*v.w);
    }
    #pragma unroll
    for (int off = 32; off >= 1; off >>= 1) {
        s  += __shfl_down(s, off, 64);
        ss += __shfl_down(ss, off, 64);
    }
    __shared__ float rs[4], rss[4];
    int wid = tid >> 6, lane = tid & 63;
    if (lane == 0) { rs[wid] = s; rss[wid] = ss; }
    __syncthreads();
    if (tid == 0) {
        part[c] = make_float2(rs[0] + rs[1] + rs[2] + rs[3],
                              rss[0] + rss[1] + rss[2] + rss[3]);
    }
}

// ---------------------------------------------------------------------------
// Kernel 2: prep — blocks 0..255: GN-normalize + transpose x -> Xt[n][c] bf16
//           blocks 256..267: qkvw f32->bf16;  blocks 268..271: projw f32->bf16
// ---------------------------------------------------------------------------
__global__ __launch_bounds__(256) void prep_kernel(
    const float* __restrict__ X, const float2* __restrict__ part,
    const float* __restrict__ gamma, const float* __restrict__ beta,
    const float* __restrict__ qkvw, const float* __restrict__ projw,
    unsigned short* __restrict__ Xt, unsigned short* __restrict__ Wqb,
    unsigned short* __restrict__ Wpb)
{
    int bi = blockIdx.x, tid = threadIdx.x;
    if (bi >= 256) {
        const float* src; unsigned short* dst;
        if (bi < 268) { src = qkvw + (size_t)(bi - 256) * 16384; dst = Wqb + (size_t)(bi - 256) * 16384; }
        else          { src = projw + (size_t)(bi - 268) * 16384; dst = Wpb + (size_t)(bi - 268) * 16384; }
        #pragma unroll
        for (int i = 0; i < 16; i++) {
            float4 v = *(const float4*)(src + (size_t)tid * 4 + (size_t)i * 1024);
            short4v w;
            w[0] = (short)f2bf(v.x); w[1] = (short)f2bf(v.y);
            w[2] = (short)f2bf(v.z); w[3] = (short)f2bf(v.w);
            *(short4v*)(dst + (size_t)tid * 4 + (size_t)i * 1024) = w;
        }
        return;
    }
    __shared__ float plds[64 * 65];
    __shared__ float gmean[8], grstd[8];
    int ci = bi >> 6, ni = bi & 63;
    if (tid < 8) {
        int g = ci * 8 + tid;
        float s = 0.f, ss = 0.f;
        #pragma unroll
        for (int k = 0; k < 8; k++) {
            float2 p = part[g * 8 + k];
            s += p.x; ss += p.y;
        }
        float mean = s * (1.f / 32768.f);
        float var  = ss * (1.f / 32768.f) - mean * mean;
        gmean[tid] = mean;
        grstd[tid] = rsqrtf(var + 1e-5f);
    }
    __syncthreads();
    #pragma unroll
    for (int i = 0; i < 4; i++) {
        int cl = (tid >> 4) + i * 16;
        int c  = ci * 64 + cl;
        int gl = cl >> 3;
        float scv = gamma[c] * grstd[gl];
        float tcv = beta[c] - gmean[gl] * scv;
        float4 v = *(const float4*)(X + (size_t)c * NTOK + ni * 64 + (tid & 15) * 4);
        float* row = plds + cl * 65 + (tid & 15) * 4;
        row[0] = v.x * scv + tcv; row[1] = v.y * scv + tcv;
        row[2] = v.z * scv + tcv; row[3] = v.w * scv + tcv;
    }
    __syncthreads();
    int nw = tid >> 2, c4 = (tid & 3) * 16;
    unsigned short tmp[16];
    #pragma unroll
    for (int i = 0; i < 16; i++) tmp[i] = f2bf(plds[(c4 + i) * 65 + nw]);
    unsigned short* dst = Xt + (size_t)(ni * 64 + nw) * CCH + ci * 64 + c4;
    *(short8*)dst       = *(short8*)&tmp[0];
    *(short8*)(dst + 8) = *(short8*)&tmp[8];
}

// ---------------------------------------------------------------------------
// Kernel 3: QKV GEMM via MFMA, direct-to-reg frags. Writes Qb[h][n][32]
// (xQSCALE), Kb[h][n][32], Vt[h][32][n] (V via same-wave LDS transpose).
// ---------------------------------------------------------------------------
__global__ __launch_bounds__(256) void qkv_mfma_kernel(
    const unsigned short* __restrict__ Wqb, const unsigned short* __restrict__ Xt,
    const float* __restrict__ qkvb,
    unsigned short* __restrict__ Qb, unsigned short* __restrict__ Kbf,
    unsigned short* __restrict__ Vtb)
{
    __shared__ __align__(16) char vlds[16384];
    const int tid = threadIdx.x;
    const int wid = tid >> 6, lane = tid & 63;
    const int l31 = lane & 31, hi = lane >> 5;
    const int bo = blockIdx.x >> 5, ng = blockIdx.x & 31;
    const int o0 = bo * 32;
    const int n0 = ng * 128 + wid * 32;

    const unsigned short* ap = Xt + (size_t)(n0 + l31) * CCH + hi * 8;
    const unsigned short* bp = Wqb + (size_t)(o0 + l31) * CCH + hi * 8;

    f32x16 acc;
    #pragma unroll
    for (int i = 0; i < 16; i++) acc[i] = 0.f;
    #pragma unroll 4
    for (int ks = 0; ks < 16; ks++) {
        short8 af = *(const short8*)(ap + ks * 16);
        short8 bf = *(const short8*)(bp + ks * 16);
        acc = __builtin_amdgcn_mfma_f32_32x32x16_bf16(af, bf, acc, 0, 0, 0);
    }

    const int t3 = bo >> 3;
    const int h  = (o0 >> 5) & 7;
    const float bias = qkvb[o0 + l31];

    if (t3 != 2) {
        unsigned short* dst = ((t3 == 0) ? Qb : Kbf) + (size_t)h * NTOK * HD + l31;
        const float scl = (t3 == 0) ? QSCALE : 1.0f;
        #pragma unroll
        for (int r = 0; r < 16; r++) {
            int n = n0 + CROW(r, hi);
            dst[(size_t)n * HD] = f2bf((acc[r] + bias) * scl);
        }
    } else {
        char* my = vlds + wid * 4096;
        #pragma unroll
        for (int r = 0; r < 16; r++) {
            int row = CROW(r, hi);
            *(float*)(my + row * 128 + ((l31 * 4) ^ ((row & 7) << 4))) = acc[r] + bias;
        }
        unsigned short tmp[16];
        #pragma unroll
        for (int i = 0; i < 16; i++) {
            int n = hi * 16 + i;
            tmp[i] = f2bf(*(const float*)(my + n * 128 + ((l31 * 4) ^ ((n & 7) << 4))));
        }
        unsigned short* vd = Vtb + ((size_t)h * HD + l31) * NTOK + n0 + hi * 16;
        *(short8*)vd       = *(short8*)&tmp[0];
        *(short8*)(vd + 8) = *(short8*)&tmp[8];
    }
}

// ---------------------------------------------------------------------------
// Kernel 4: flash attention — NO LDS in the main loop. Each wave covers 64
// q-columns (2 Q-frags) over its private 1024-key quarter. K/V fragments are
// loaded DIRECTLY global->registers (per-lane dwordx4; the old LDS staging
// was a same-lane round-trip with zero redistribution). Manual 2x-unrolled
// software pipeline with NAMED prefetch registers (rule #20: no runtime-
// indexed register arrays). exp via v_exp_f32; P exchange via
// v_permlane32_swap. Cross-wave combine through a small LDS stash.
// ---------------------------------------------------------------------------
__global__ __launch_bounds__(256) void attn_mfma_kernel(
    const unsigned short* __restrict__ Qb, const unsigned short* __restrict__ Kbf,
    const unsigned short* __restrict__ Vtb, unsigned short* __restrict__ att_t)
{
    __shared__ float stash[4][64][37];    // [wave][q][d], 148B row stride
    __shared__ float lsum[4][64];
    const int tid = threadIdx.x;
    const int wid = tid >> 6, lane = tid & 63;
    const int l31 = lane & 31, hi = lane >> 5;
    const int bid = blockIdx.x;          // 512 blocks
    const int h    = bid & 7;            // head -> XCD (bid%8)
    const int g    = bid >> 3;           // 0..63
    const int base = g & 15;
    const int j0   = (g >> 4) * 64;      // 0,64,128,192

    // K: row = wid*1024 + t*32 + l31, elems [hi*8..) and [16+hi*8..)
    const unsigned short* kp = Kbf + ((size_t)h * NTOK + wid * 1024 + l31) * HD + hi * 8;
    // V^T: row d = l31, key elems wid*1024 + t*32 + hi*8 (and +16)
    const unsigned short* vp = Vtb + ((size_t)h * HD + l31) * NTOK + wid * 1024 + hi * 8;

    // Q frags: q-col j (A: j=l31, B: j=32+l31); token = base + 16*(j0+j)
    const unsigned short* qpA = Qb + ((size_t)h * NTOK + base + 16 * (size_t)(j0 + l31)) * HD + hi * 8;
    const unsigned short* qpB = qpA + (size_t)32 * 16 * HD;
    short8 qfA0 = *(const short8*)qpA;
    short8 qfA1 = *(const short8*)(qpA + 16);
    short8 qfB0 = *(const short8*)qpB;
    short8 qfB1 = *(const short8*)(qpB + 16);

    f32x16 oaccA, oaccB;
    #pragma unroll
    for (int i = 0; i < 16; i++) { oaccA[i] = 0.f; oaccB[i] = 0.f; }
    const f32x16 zero = oaccA;
    float lA = 0.f, lB = 0.f;

#define ATTN_BODY(KF0, KF1, VF0, VF1) do {                                     \
    f32x16 sA = __builtin_amdgcn_mfma_f32_32x32x16_bf16(KF0, qfA0, zero, 0, 0, 0); \
    sA = __builtin_amdgcn_mfma_f32_32x32x16_bf16(KF1, qfA1, sA, 0, 0, 0);      \
    f32x16 sB = __builtin_amdgcn_mfma_f32_32x32x16_bf16(KF0, qfB0, zero, 0, 0, 0); \
    sB = __builtin_amdgcn_mfma_f32_32x32x16_bf16(KF1, qfB1, sB, 0, 0, 0);      \
    float pA[16], pB[16];                                                      \
    _Pragma("unroll") for (int r = 0; r < 16; r++) pA[r] = exp2hw(sA[r]);      \
    _Pragma("unroll") for (int r = 0; r < 16; r++) pB[r] = exp2hw(sB[r]);      \
    lA += (((pA[0]+pA[1]) + (pA[2]+pA[3])) + ((pA[4]+pA[5]) + (pA[6]+pA[7])))  \
        + (((pA[8]+pA[9]) + (pA[10]+pA[11])) + ((pA[12]+pA[13]) + (pA[14]+pA[15]))); \
    lB += (((pB[0]+pB[1]) + (pB[2]+pB[3])) + ((pB[4]+pB[5]) + (pB[6]+pB[7])))  \
        + (((pB[8]+pB[9]) + (pB[10]+pB[11])) + ((pB[12]+pB[13]) + (pB[14]+pB[15]))); \
    _Pragma("unroll")                                                          \
    for (int m = 0; m < 2; m++) {                                              \
        const int b8 = m * 8;                                                  \
        unsigned A0 = packbf2(pA[b8 + 0], pA[b8 + 1]);                         \
        unsigned A1 = packbf2(pA[b8 + 2], pA[b8 + 3]);                         \
        unsigned B0 = packbf2(pA[b8 + 4], pA[b8 + 5]);                         \
        unsigned B1 = packbf2(pA[b8 + 6], pA[b8 + 7]);                         \
        asm volatile("v_permlane32_swap_b32 %0, %1" : "+v"(A0), "+v"(B0));     \
        asm volatile("v_permlane32_swap_b32 %0, %1" : "+v"(A1), "+v"(B1));     \
        union { unsigned u[4]; short8 v; } pa;                                 \
        pa.u[0] = A0; pa.u[1] = A1; pa.u[2] = B0; pa.u[3] = B1;                \
        oaccA = __builtin_amdgcn_mfma_f32_32x32x16_bf16(                       \
            pa.v, (m == 0) ? (VF0) : (VF1), oaccA, 0, 0, 0);                   \
    }                                                                          \
    _Pragma("unroll")                                                          \
    for (int m = 0; m < 2; m++) {                                              \
        const int b8 = m * 8;                                                  \
        unsigned A0 = packbf2(pB[b8 + 0], pB[b8 + 1]);                         \
        unsigned A1 = packbf2(pB[b8 + 2], pB[b8 + 3]);                         \
        unsigned B0 = packbf2(pB[b8 + 4], pB[b8 + 5]);                         \
        unsigned B1 = packbf2(pB[b8 + 6], pB[b8 + 7]);                         \
        asm volatile("v_permlane32_swap_b32 %0, %1" : "+v"(A0), "+v"(B0));     \
        asm volatile("v_permlane32_swap_b32 %0, %1" : "+v"(A1), "+v"(B1));     \
        union { unsigned u[4]; short8 v; } pa;                                 \
        pa.u[0] = A0; pa.u[1] = A1; pa.u[2] = B0; pa.u[3] = B1;                \
        oaccB = __builtin_amdgcn_mfma_f32_32x32x16_bf16(                       \
            pa.v, (m == 0) ? (VF0) : (VF1), oaccB, 0, 0, 0);                   \
    }                                                                          \
} while (0)

    // software pipeline, prefetch distance 1, all names static
    short8 kf0a = *(const short8*)(kp);
    short8 kf1a = *(const short8*)(kp + 16);
    short8 vf0a = *(const short8*)(vp);
    short8 vf1a = *(const short8*)(vp + 16);

    #pragma unroll 1
    for (int t = 0; t < 32; t += 2) {
        const int t1 = t + 1;                       // <= 31
        short8 kf0b = *(const short8*)(kp + t1 * 1024);
        short8 kf1b = *(const short8*)(kp + t1 * 1024 + 16);
        short8 vf0b = *(const short8*)(vp + t1 * 32);
        short8 vf1b = *(const short8*)(vp + t1 * 32 + 16);
        ATTN_BODY(kf0a, kf1a, vf0a, vf1a);
        const int t2 = (t + 2 < 32) ? (t + 2) : 31; // clamp: redundant reload
        kf0a = *(const short8*)(kp + t2 * 1024);
        kf1a = *(const short8*)(kp + t2 * 1024 + 16);
        vf0a = *(const short8*)(vp + t2 * 32);
        vf1a = *(const short8*)(vp + t2 * 32 + 16);
        ATTN_BODY(kf0b, kf1b, vf0b, vf1b);
    }
#undef ATTN_BODY

    // ---- in-block combine ----
    lA += __shfl_xor(lA, 32, 64);
    lB += __shfl_xor(lB, 32, 64);
    #pragma unroll
    for (int r = 0; r < 16; r++) {
        int rowA = CROW(r, hi);
        stash[wid][rowA][l31] = oaccA[r];
        stash[wid][rowA + 32][l31] = oaccB[r];
    }
    if (lane < 32) { lsum[wid][l31] = lA; lsum[wid][32 + l31] = lB; }
    __syncthreads();

    // thread: d = tid>>3 (0..31), q8 = (tid&7)*8 -> one short8 row-store
    const int d = tid >> 3, q8 = (tid & 7) * 8;
    unsigned short ob[8];
    #pragma unroll
    for (int i = 0; i < 8; i++) {
        int q = q8 + i;
        float lt = (lsum[0][q] + lsum[1][q]) + (lsum[2][q] + lsum[3][q]);
        float a = (stash[0][q][d] + stash[1][q][d]) + (stash[2][q][d] + stash[3][q][d]);
        ob[i] = f2bf(a / lt);
    }
    // att_t[p][c]: p = base*256 + h*32 + d, c = j0 + q8 .. +7
    unsigned short* dst = att_t + (size_t)(base * 256 + h * 32 + d) * CCH + j0 + q8;
    *(short8*)dst = *(short8*)ob;
}

// ---------------------------------------------------------------------------
// Kernel 5: output projection via MFMA + bias + residual.
// ---------------------------------------------------------------------------
__global__ __launch_bounds__(256) void proj_mfma_kernel(
    const unsigned short* __restrict__ Wpb, const unsigned short* __restrict__ att_t,
    const float* __restrict__ X, const float* __restrict__ pb,
    float* __restrict__ out)
{
    const int tid = threadIdx.x;
    const int wid = tid >> 6, lane = tid & 63;
    const int l31 = lane & 31, hi = lane >> 5;
    const int ot = blockIdx.x >> 5, pg = blockIdx.x & 31;
    const int o0 = ot * 32;
    const int p0 = pg * 128 + wid * 32;

    const unsigned short* ap = Wpb + (size_t)(o0 + l31) * CCH + hi * 8;
    const unsigned short* bp = att_t + (size_t)(p0 + l31) * CCH + hi * 8;

    f32x16 acc;
    #pragma unroll
    for (int i = 0; i < 16; i++) acc[i] = 0.f;
    #pragma unroll 4
    for (int ks = 0; ks < 16; ks++) {
        short8 af = *(const short8*)(ap + ks * 16);
        short8 bf = *(const short8*)(bp + ks * 16);
        acc = __builtin_amdgcn_mfma_f32_32x32x16_bf16(af, bf, acc, 0, 0, 0);
    }
    #pragma unroll
    for (int r = 0; r < 16; r++) {
        int o = o0 + CROW(r, hi);
        size_t ofs = (size_t)o * NTOK + p0 + l31;
        out[ofs] = X[ofs] + pb[o] + acc[r];
    }
}

// ---------------------------------------------------------------------------
extern "C" void kernel_launch(void* const* d_in, const int* in_sizes, int n_in,
                              void* d_out, int out_size, void* d_ws, size_t ws_size,
                              hipStream_t stream)
{
    const float* x     = (const float*)d_in[0];
    const float* gamma = (const float*)d_in[1];
    const float* beta  = (const float*)d_in[2];
    const float* qkvw  = (const float*)d_in[3];
    const float* qkvb  = (const float*)d_in[4];
    const float* projw = (const float*)d_in[5];
    const float* projb = (const float*)d_in[6];
    float* out = (float*)d_out;

    char* ws = (char*)d_ws;
    const size_t MB = 1024 * 1024;
    float2* part = (float2*)ws;                                    // 2KB
    unsigned short* Xt    = (unsigned short*)(ws + 4096);          // 2MB [4096][256]
    unsigned short* Wqb   = (unsigned short*)(ws + 4096 + 2*MB);   // 384KB [768][256]
    unsigned short* Wpb   = Wqb + 768 * 256;                       // 128KB [256][256]
    unsigned short* Qb    = Wpb + 256 * 256;                       // 2MB [8][4096][32]
    unsigned short* Kbf   = Qb + HEADS * NTOK * HD;                // 2MB
    unsigned short* Vtb   = Kbf + HEADS * NTOK * HD;               // 2MB [8][32][4096]
    unsigned short* att_t = Vtb + HEADS * NTOK * HD;               // 2MB [4096][256]

    gn_part_kernel<<<256, 256, 0, stream>>>(x, part);
    prep_kernel<<<272, 256, 0, stream>>>(x, part, gamma, beta, qkvw, projw, Xt, Wqb, Wpb);
    qkv_mfma_kernel<<<768, 256, 0, stream>>>(Wqb, Xt, qkvb, Qb, Kbf, Vtb);
    attn_mfma_kernel<<<512, 256, 0, stream>>>(Qb, Kbf, Vtb, att_t);
    proj_mfma_kernel<<<256, 256, 0, stream>>>(Wpb, att_t, x, projb, out);
}